// Round 16
// baseline (480.117 us; speedup 1.0000x reference)
//
#include <hip/hip_runtime.h>
#include <hip/hip_bf16.h>
#include <math.h>

// Problem constants (fixed by setup_inputs: B=8, H=W=56)
#define BB 8
#define HH 56
#define WW 56
#define LL (HH*WW)          // 3136
#define DMODEL 384
#define DINNER 768
#define NH 12
#define HD 64
#define DS 64
#define CDIM (DINNER + 2*DS)    // 896
#define NPROJ (2*DINNER + 2*DS + NH) // 1676
#define NPAD 1792           // NPROJ padded to multiple of 128
#define MTOT (BB*LL)        // 25088
#define LN_EPS 1e-5f
#define NCG (CDIM/8)        // 112 channel-groups for conv
#define NDG (DINNER/8)      // 96 channel-groups for dxpool
#define SPLITL 7            // L-chunks for hstate (3136/7 = 448)

typedef __attribute__((ext_vector_type(8))) _Float16 f16x8;
typedef __attribute__((ext_vector_type(4))) float f32x4;

__device__ __forceinline__ ushort f2hu(float v) {
    union { _Float16 h; ushort u; } cv; cv.h = (_Float16)v; return cv.u;
}
__device__ __forceinline__ float hu2f(ushort u) {
    union { ushort u; _Float16 h; } cv; cv.u = u; return (float)cv.h;
}

__device__ __forceinline__ void gload_lds16(const ushort* gp, ushort* lp) {
    __builtin_amdgcn_global_load_lds(
        (const __attribute__((address_space(1))) void*)gp,
        (__attribute__((address_space(3))) void*)lp, 16, 0, 0);
}

__device__ __forceinline__ int xcd_swz(int bid, int nwg) {
    int q = nwg >> 3, r = nwg & 7;
    int xcd = bid & 7, idx = bid >> 3;
    return (xcd < r ? xcd * (q + 1) : r * (q + 1) + (xcd - r) * q) + idx;
}

// ---------------- cast kernels: fp32 -> f16 -------------------------------------
__global__ __launch_bounds__(256) void k_cast_x(
    const float4* __restrict__ in, ushort4* __restrict__ out)
{
    int i = blockIdx.x * 256 + threadIdx.x;
    float4 v = in[i];
    ushort4 h;
    h.x = f2hu(v.x); h.y = f2hu(v.y); h.z = f2hu(v.z); h.w = f2hu(v.w);
    out[i] = h;
}

#define W1Q (NPAD*DMODEL/4)    // 172032
#define W2Q (DMODEL*DINNER/4)  // 73728
#define CWQ (NCG*72/4)         // 2016
__global__ __launch_bounds__(256) void k_cast_w(
    const float* __restrict__ w1src, const float* __restrict__ w2src,
    const float* __restrict__ cwsrc,
    ushort4* __restrict__ w1dst, ushort4* __restrict__ w2dst,
    float* __restrict__ cwrdst)
{
    int i = blockIdx.x * 256 + threadIdx.x;
    if (i < W1Q) {
        int n = i / (DMODEL / 4);
        int k = (i % (DMODEL / 4)) * 4;
        ushort4 h = {0,0,0,0};
        if (n < NPROJ) {
            float4 v = *(const float4*)(w1src + (size_t)n * DMODEL + k);
            h.x = f2hu(v.x); h.y = f2hu(v.y); h.z = f2hu(v.z); h.w = f2hu(v.w);
        }
        w1dst[i] = h;
    } else if (i < W1Q + W2Q) {
        int t = i - W1Q;
        float4 v = ((const float4*)w2src)[t];
        ushort4 h;
        h.x = f2hu(v.x); h.y = f2hu(v.y); h.z = f2hu(v.z); h.w = f2hu(v.w);
        w2dst[t] = h;
    } else if (i < W1Q + W2Q + CWQ) {
        int t = i - W1Q - W2Q;
#pragma unroll
        for (int k = 0; k < 4; ++k) {
            int e = 4 * t + k;
            int cgx = e / 72;
            int rr = e % 72;
            int tap = rr >> 3, q = rr & 7;
            cwrdst[e] = cwsrc[(cgx * 8 + q) * 9 + tap];
        }
    }
}

// ---------------- GEMM1 (MFMA f16, BM=256 BN=128 BK=64, XCD-chunked, swizzled) --
// 256 MFMA per barrier-pair (2x prior): halves barrier-drain events per FLOP
// (m233: stage+drain is the ~72% fixed cost).  Verified XOR involution kept.
#define G1_NT (NPAD/128)    // 14 n-tiles
#define G1_NWG (G1_NT * (MTOT/256))  // 1372
__global__ __launch_bounds__(256) void k_gemm1_mfma(
    const ushort* __restrict__ xh, const ushort* __restrict__ wh,
    const float* __restrict__ dt_bias,
    ushort* __restrict__ zbuf, ushort* __restrict__ xbcbuf, float* __restrict__ dtbuf)
{
    __shared__ ushort As[2][256 * 32];   // 32 KB
    __shared__ ushort Bs[2][128 * 32];   // 16 KB
    const int w = xcd_swz(blockIdx.x, G1_NWG);
    const int m0 = (w / G1_NT) * 256;
    const int n0 = (w % G1_NT) * 128;
    const int tid = threadIdx.x;
    const int wid = tid >> 6;
    const int lane = tid & 63;
    const int r = lane & 15;
    const int quad = lane >> 4;
    const int wm = (wid >> 1) * 128;
    const int wn = (wid & 1) * 64;
    const int lrow = lane >> 2;
    const int lcol = (((lane & 3) ^ ((lane >> 3) & 3)) * 8);
    const int sxr = (r >> 1) & 3;

    f32x4 acc[8][4];
#pragma unroll
    for (int i = 0; i < 8; ++i)
#pragma unroll
        for (int j = 0; j < 4; ++j) acc[i][j] = (f32x4){0.f, 0.f, 0.f, 0.f};

    for (int k0 = 0; k0 < DMODEL; k0 += 64) {
#pragma unroll
        for (int half = 0; half < 2; ++half) {
#pragma unroll
            for (int inst = 0; inst < 4; ++inst) {       // A: wave covers 64 rows
                const int R = wid * 64 + inst * 16;
                gload_lds16(xh + (size_t)(m0 + R + lrow) * DMODEL + k0 + half * 32 + lcol,
                            As[half] + R * 32);
            }
#pragma unroll
            for (int inst = 0; inst < 2; ++inst) {       // B: wave covers 32 rows
                const int R = wid * 32 + inst * 16;
                gload_lds16(wh + (size_t)(n0 + R + lrow) * DMODEL + k0 + half * 32 + lcol,
                            Bs[half] + R * 32);
            }
        }
        __syncthreads();

#pragma unroll
        for (int kk = 0; kk < 2; ++kk) {
            f16x8 af[8], bfr[4];
#pragma unroll
            for (int t = 0; t < 8; ++t)
                af[t]  = *(const f16x8*)(As[kk] + (wm + t * 16 + r) * 32 + ((quad ^ sxr) * 8));
#pragma unroll
            for (int t = 0; t < 4; ++t)
                bfr[t] = *(const f16x8*)(Bs[kk] + (wn + t * 16 + r) * 32 + ((quad ^ sxr) * 8));
#pragma unroll
            for (int i = 0; i < 8; ++i)
#pragma unroll
                for (int j = 0; j < 4; ++j)
                    acc[i][j] = __builtin_amdgcn_mfma_f32_16x16x32_f16(af[i], bfr[j], acc[i][j], 0, 0, 0);
        }
        __syncthreads();
    }
#pragma unroll
    for (int i = 0; i < 8; ++i) {
#pragma unroll
        for (int j = 0; j < 4; ++j) {
            int n = n0 + wn + j * 16 + r;
            if (n >= NPROJ) continue;
#pragma unroll
            for (int v = 0; v < 4; ++v) {
                int m = m0 + wm + i * 16 + quad * 4 + v;
                float val = acc[i][j][v];
                if (n < DINNER) {
                    zbuf[(size_t)m * DINNER + n] = f2hu(val);
                } else if (n < DINNER + CDIM) {
                    xbcbuf[(size_t)m * CDIM + (n - DINNER)] = f2hu(val);
                } else {
                    int h = n - (DINNER + CDIM);
                    float t = val + dt_bias[h];
                    float sp = (t > 20.f) ? t : log1pf(expf(t));
                    dtbuf[(size_t)m * NH + h] = sp;
                }
            }
        }
    }
}

// ---------------- GEMM2 (MFMA f16, BM=256 BN=128 BK=64, XCD-chunked, swizzled) --
#define G2_NT (DMODEL/128)  // 3 n-tiles
#define G2_NWG (G2_NT * (MTOT/256))  // 294
__global__ __launch_bounds__(256) void k_gemm2_mfma(
    const ushort* __restrict__ gn, const ushort* __restrict__ wh,
    float* __restrict__ out)
{
    __shared__ ushort As[2][256 * 32];
    __shared__ ushort Bs[2][128 * 32];
    const int w = xcd_swz(blockIdx.x, G2_NWG);
    const int m0 = (w / G2_NT) * 256;
    const int n0 = (w % G2_NT) * 128;
    const int tid = threadIdx.x;
    const int wid = tid >> 6;
    const int lane = tid & 63;
    const int r = lane & 15;
    const int quad = lane >> 4;
    const int wm = (wid >> 1) * 128;
    const int wn = (wid & 1) * 64;
    const int lrow = lane >> 2;
    const int lcol = (((lane & 3) ^ ((lane >> 3) & 3)) * 8);
    const int sxr = (r >> 1) & 3;

    f32x4 acc[8][4];
#pragma unroll
    for (int i = 0; i < 8; ++i)
#pragma unroll
        for (int j = 0; j < 4; ++j) acc[i][j] = (f32x4){0.f, 0.f, 0.f, 0.f};

    for (int k0 = 0; k0 < DINNER; k0 += 64) {
#pragma unroll
        for (int half = 0; half < 2; ++half) {
#pragma unroll
            for (int inst = 0; inst < 4; ++inst) {
                const int R = wid * 64 + inst * 16;
                gload_lds16(gn + (size_t)(m0 + R + lrow) * DINNER + k0 + half * 32 + lcol,
                            As[half] + R * 32);
            }
#pragma unroll
            for (int inst = 0; inst < 2; ++inst) {
                const int R = wid * 32 + inst * 16;
                gload_lds16(wh + (size_t)(n0 + R + lrow) * DINNER + k0 + half * 32 + lcol,
                            Bs[half] + R * 32);
            }
        }
        __syncthreads();

#pragma unroll
        for (int kk = 0; kk < 2; ++kk) {
            f16x8 af[8], bfr[4];
#pragma unroll
            for (int t = 0; t < 8; ++t)
                af[t]  = *(const f16x8*)(As[kk] + (wm + t * 16 + r) * 32 + ((quad ^ sxr) * 8));
#pragma unroll
            for (int t = 0; t < 4; ++t)
                bfr[t] = *(const f16x8*)(Bs[kk] + (wn + t * 16 + r) * 32 + ((quad ^ sxr) * 8));
#pragma unroll
            for (int i = 0; i < 8; ++i)
#pragma unroll
                for (int j = 0; j < 4; ++j)
                    acc[i][j] = __builtin_amdgcn_mfma_f32_16x16x32_f16(af[i], bfr[j], acc[i][j], 0, 0, 0);
        }
        __syncthreads();
    }
#pragma unroll
    for (int i = 0; i < 8; ++i) {
#pragma unroll
        for (int j = 0; j < 4; ++j) {
            int n = n0 + wn + j * 16 + r;
#pragma unroll
            for (int v = 0; v < 4; ++v) {
                int m = m0 + wm + i * 16 + quad * 4 + v;
                out[(size_t)m * DMODEL + n] = acc[i][j][v];
            }
        }
    }
}

// ---------------- depthwise 3x3 conv + bias + SiLU, 4 pixels x 8 ch per thread --
__global__ __launch_bounds__(256) void k_conv(
    const ushort* __restrict__ xbc, const float* __restrict__ cwr,
    const float* __restrict__ cb, ushort* __restrict__ out)
{
    const int gid = blockIdx.x * 256 + threadIdx.x;
    const int cg  = gid % NCG;
    const int pq  = gid / NCG;
    const int b   = pq / (LL / 4);
    const int rem = pq % (LL / 4);
    const int i   = rem / (WW / 4);
    const int j0  = (rem % (WW / 4)) * 4;
    const int c0  = cg * 8;

    float acc[4][8];
    {
        float4 b0 = *(const float4*)(cb + c0);
        float4 b1 = *(const float4*)(cb + c0 + 4);
#pragma unroll
        for (int p = 0; p < 4; ++p) {
            acc[p][0]=b0.x; acc[p][1]=b0.y; acc[p][2]=b0.z; acc[p][3]=b0.w;
            acc[p][4]=b1.x; acc[p][5]=b1.y; acc[p][6]=b1.z; acc[p][7]=b1.w;
        }
    }
    const size_t rowbase = (size_t)b * LL;
#pragma unroll
    for (int ky = 0; ky < 3; ++ky) {
        int ii = i + ky - 1;
        if (ii < 0 || ii >= HH) continue;
        float w[24];
        const float* wr = cwr + (cg * 9 + ky * 3) * 8;
#pragma unroll
        for (int t = 0; t < 6; ++t)
            *(float4*)(w + t * 4) = *(const float4*)(wr + t * 4);
        float xc[6][8];
#pragma unroll
        for (int col = 0; col < 6; ++col) {
            int jj = j0 - 1 + col;
            if (jj >= 0 && jj < WW) {
                union { int4 q; ushort u[8]; } xv;
                xv.q = *(const int4*)(xbc + (rowbase + ii * WW + jj) * CDIM + c0);
#pragma unroll
                for (int q = 0; q < 8; ++q) xc[col][q] = hu2f(xv.u[q]);
            } else {
#pragma unroll
                for (int q = 0; q < 8; ++q) xc[col][q] = 0.f;
            }
        }
#pragma unroll
        for (int p = 0; p < 4; ++p)
#pragma unroll
            for (int kx = 0; kx < 3; ++kx)
#pragma unroll
                for (int q = 0; q < 8; ++q)
                    acc[p][q] += w[kx * 8 + q] * xc[p + kx][q];
    }
#pragma unroll
    for (int p = 0; p < 4; ++p) {
        union { int4 q; ushort u[8]; } o;
#pragma unroll
        for (int q = 0; q < 8; ++q) {
            float s = acc[p][q] / (1.f + expf(-acc[p][q]));
            o.u[q] = f2hu(s);
        }
        *(int4*)(out + (rowbase + i * WW + j0 + p) * CDIM + c0) = o.q;
    }
}

// ---------------- fused dx + 3x3 count-norm avg pool, 4 pixels x 8 ch -----------
__global__ __launch_bounds__(256) void k_dxpool(
    const ushort* __restrict__ xbc_conv, const float* __restrict__ dtbuf,
    const float* __restrict__ A_log, ushort* __restrict__ dxp)
{
    const int gid = blockIdx.x * 256 + threadIdx.x;
    const int cg  = gid % NDG;
    const int pq  = gid / NDG;
    const int b   = pq / (LL / 4);
    const int rem = pq % (LL / 4);
    const int i   = rem / (WW / 4);
    const int j0  = (rem % (WW / 4)) * 4;
    const int c0  = cg * 8;
    const int h   = c0 >> 6;

    float Ah[8];
    {
        float4 a0 = *(const float4*)(A_log + c0);
        float4 a1 = *(const float4*)(A_log + c0 + 4);
        Ah[0]=a0.x; Ah[1]=a0.y; Ah[2]=a0.z; Ah[3]=a0.w;
        Ah[4]=a1.x; Ah[5]=a1.y; Ah[6]=a1.z; Ah[7]=a1.w;
    }
#pragma unroll
    for (int q = 0; q < 8; ++q) Ah[q] = -expf(Ah[q]);

    float sum[4][8];
#pragma unroll
    for (int p = 0; p < 4; ++p)
#pragma unroll
        for (int q = 0; q < 8; ++q) sum[p][q] = 0.f;

    const size_t rowbase = (size_t)b * LL;
#pragma unroll
    for (int ky = 0; ky < 3; ++ky) {
        int ii = i + ky - 1;
        if (ii < 0 || ii >= HH) continue;
        float dtv[6];
        float xc[6][8];
#pragma unroll
        for (int col = 0; col < 6; ++col) {
            int jj = j0 - 1 + col;
            if (jj >= 0 && jj < WW) {
                dtv[col] = dtbuf[(rowbase + ii * WW + jj) * NH + h];
                union { int4 q; ushort u[8]; } xv;
                xv.q = *(const int4*)(xbc_conv + (rowbase + ii * WW + jj) * CDIM + c0);
#pragma unroll
                for (int q = 0; q < 8; ++q) xc[col][q] = hu2f(xv.u[q]);
            } else {
                dtv[col] = 0.f;
#pragma unroll
                for (int q = 0; q < 8; ++q) xc[col][q] = 0.f;
            }
        }
#pragma unroll
        for (int p = 0; p < 4; ++p)
#pragma unroll
            for (int kx = 0; kx < 3; ++kx)
#pragma unroll
                for (int q = 0; q < 8; ++q)
                    sum[p][q] += dtv[p + kx] * xc[p + kx][q];
    }
    const int rv = 3 - (i == 0) - (i == HH - 1);
#pragma unroll
    for (int p = 0; p < 4; ++p) {
        int j = j0 + p;
        int cv = 3 - (j == 0) - (j == WW - 1);
        float inv = 1.f / (float)(rv * cv);
        union { int4 q; ushort u[8]; } o;
#pragma unroll
        for (int q = 0; q < 8; ++q)
            o.u[q] = f2hu(Ah[q] * sum[p][q] * inv);
        *(int4*)(dxp + (((size_t)b * NH + h) * LL + i * WW + j) * HD + (c0 & 63)) = o.q;
    }
}

// ---------------- h_state via MFMA (no atomics): Ht_part[d][s] ------------------
#define LDSP 33
__global__ __launch_bounds__(256) void k_hstate_mfma(
    const ushort* __restrict__ xbc_conv, const ushort* __restrict__ dxp,
    float* __restrict__ hpart)
{
    __shared__ ushort DsT[64 * LDSP];   // [d][l]
    __shared__ ushort BsT[64 * LDSP];   // [s][l]
    const int lc = blockIdx.x;          // 0..6
    const int bh = blockIdx.y;          // 0..95
    const int b = bh / NH;
    const int tid = threadIdx.x;
    const int wid = tid >> 6;
    const int lane = tid & 63;
    const int r = lane & 15;
    const int quad = lane >> 4;
    const int wd = (wid >> 1) * 32;
    const int wsn = (wid & 1) * 32;
    const int lt = tid >> 3;
    const int sg = (tid & 7) * 8;

    f32x4 acc[2][2];
#pragma unroll
    for (int i = 0; i < 2; ++i)
#pragma unroll
        for (int j = 0; j < 2; ++j) acc[i][j] = (f32x4){0.f, 0.f, 0.f, 0.f};

    const int l_base = lc * (LL / SPLITL);
    for (int step = 0; step < (LL / SPLITL) / 32; ++step) {
        int l0 = l_base + step * 32;
        union { int4 q; ushort u[8]; } dv, bv;
        dv.q = *(const int4*)(dxp + (((size_t)bh) * LL + l0 + lt) * HD + sg);
        bv.q = *(const int4*)(xbc_conv + ((size_t)(b * LL + l0 + lt)) * CDIM + DINNER + sg);
        __syncthreads();
#pragma unroll
        for (int q = 0; q < 8; ++q) {
            DsT[(sg + q) * LDSP + lt] = dv.u[q];
            BsT[(sg + q) * LDSP + lt] = bv.u[q];
        }
        __syncthreads();
        f16x8 af[2], bf[2];
#pragma unroll
        for (int t = 0; t < 2; ++t) {
            af[t] = *(const f16x8*)(DsT + (wd + t * 16 + r) * LDSP + quad * 8);
            bf[t] = *(const f16x8*)(BsT + (wsn + t * 16 + r) * LDSP + quad * 8);
        }
#pragma unroll
        for (int i = 0; i < 2; ++i)
#pragma unroll
            for (int j = 0; j < 2; ++j)
                acc[i][j] = __builtin_amdgcn_mfma_f32_16x16x32_f16(af[i], bf[j], acc[i][j], 0, 0, 0);
    }
    float* outp = hpart + ((size_t)(lc * 96 + bh) << 12);
#pragma unroll
    for (int i = 0; i < 2; ++i)
#pragma unroll
        for (int j = 0; j < 2; ++j)
#pragma unroll
            for (int v = 0; v < 4; ++v)
                outp[(wd + i * 16 + quad * 4 + v) * 64 + (wsn + j * 16 + r)] = acc[i][j][v];
}

// ---------------- h-prep: reduce 7 partials [d][s] -> hT f16 [bh][d][s] ---------
__global__ __launch_bounds__(256) void k_hprep(
    const float* __restrict__ hpart, ushort* __restrict__ hT)
{
    int i = blockIdx.x * 256 + threadIdx.x;
    int bh = i >> 12;
    int rem = i & 4095;
    float v = 0.f;
#pragma unroll
    for (int lc = 0; lc < SPLITL; ++lc)
        v += hpart[((size_t)(lc * 96 + bh) << 12) + rem];
    hT[i] = f2hu(v);
}

// ---------------- Ch + y via MFMA (v2: LDS-staged Cm, verified swizzle) ---------
#define HTW 72
__global__ __launch_bounds__(256) void k_chy_mfma(
    const ushort* __restrict__ xbc_conv, const ushort* __restrict__ hT,
    const float* __restrict__ Dp, ushort* __restrict__ ybuf)
{
    __shared__ ushort Cs[2][256 * 32];
    __shared__ ushort Hs[64 * HTW];
    const int bh = blockIdx.y;
    const int b = bh / NH, h = bh % NH;
    const int tid = threadIdx.x;
    const int wid = tid >> 6;
    const int lane = tid & 63;
    const int r = lane & 15;
    const int quad = lane >> 4;
    const int lrow = lane >> 2;
    const int lcol = (((lane & 3) ^ ((lane >> 3) & 3)) * 8);
    const int sxr = (r >> 1) & 3;

    for (int idx = tid; idx < 512; idx += 256) {
        int row = idx >> 3, c8 = (idx & 7) * 8;
        *(int4*)(Hs + row * HTW + c8) = *(const int4*)(hT + ((size_t)bh << 12) + row * 64 + c8);
    }

    const int lbase = blockIdx.x * 256;
#pragma unroll
    for (int inst = 0; inst < 4; ++inst) {
        const int R = wid * 64 + inst * 16;
        if (lbase + R + 16 <= LL) {
#pragma unroll
            for (int kk = 0; kk < 2; ++kk) {
                gload_lds16(xbc_conv + ((size_t)(b * LL + lbase + R + lrow)) * CDIM
                                      + DINNER + DS + kk * 32 + lcol,
                            Cs[kk] + R * 32);
            }
        }
    }
    __syncthreads();

    const int chunk = blockIdx.x * 4 + wid;
    if (chunk >= 49) return;
    const int l0 = chunk * 64;
    const int wl = wid * 64;

    f32x4 acc[4][4];
#pragma unroll
    for (int i = 0; i < 4; ++i)
#pragma unroll
        for (int j = 0; j < 4; ++j) acc[i][j] = (f32x4){0.f, 0.f, 0.f, 0.f};

#pragma unroll
    for (int kk = 0; kk < 2; ++kk) {
        f16x8 af[4], bfr[4];
#pragma unroll
        for (int t = 0; t < 4; ++t) {
            af[t]  = *(const f16x8*)(Cs[kk] + (wl + t * 16 + r) * 32 + ((quad ^ sxr) * 8));
            bfr[t] = *(const f16x8*)(Hs + (t * 16 + r) * HTW + kk * 32 + quad * 8);
        }
#pragma unroll
        for (int i = 0; i < 4; ++i)
#pragma unroll
            for (int j = 0; j < 4; ++j)
                acc[i][j] = __builtin_amdgcn_mfma_f32_16x16x32_f16(af[i], bfr[j], acc[i][j], 0, 0, 0);
    }
    const float Dh = Dp[h];
#pragma unroll
    for (int i = 0; i < 4; ++i) {
#pragma unroll
        for (int j = 0; j < 4; ++j) {
            int d = j * 16 + r;
#pragma unroll
            for (int v = 0; v < 4; ++v) {
                int l = l0 + i * 16 + quad * 4 + v;
                float xv = hu2f(xbc_conv[((size_t)(b * LL + l)) * CDIM + h * HD + d]);
                ybuf[((size_t)(b * LL + l)) * DINNER + h * HD + d] = f2hu(acc[i][j][v] + xv * Dh);
            }
        }
    }
}

// ---------------- g = y*silu(z); LayerNorm(768), wave-per-row -------------------
__global__ __launch_bounds__(256) void k_gln(
    const ushort* __restrict__ ybuf, const ushort* __restrict__ zbuf,
    const float* __restrict__ nw, const float* __restrict__ nb,
    ushort* __restrict__ gnbuf)
{
    const int row = blockIdx.x * 4 + (threadIdx.x >> 6);
    const int lane = threadIdx.x & 63;
    const size_t base = (size_t)row * DINNER;

    float g[12];
    float sum = 0.f, sumsq = 0.f;
#pragma unroll
    for (int p = 0; p < 3; ++p) {
        int c = lane * 4 + p * 256;
        union { ushort4 q; ushort u[4]; } yv, zv;
        yv.q = *(const ushort4*)(ybuf + base + c);
        zv.q = *(const ushort4*)(zbuf + base + c);
#pragma unroll
        for (int q = 0; q < 4; ++q) {
            float y = hu2f(yv.u[q]);
            float z = hu2f(zv.u[q]);
            float gv = y * (z / (1.f + expf(-z)));
            g[p * 4 + q] = gv;
            sum += gv;
            sumsq += gv * gv;
        }
    }
#pragma unroll
    for (int off = 32; off > 0; off >>= 1) {
        sum += __shfl_xor(sum, off, 64);
        sumsq += __shfl_xor(sumsq, off, 64);
    }
    const float mu = sum / (float)DINNER;
    const float var = sumsq / (float)DINNER - mu * mu;
    const float rstd = rsqrtf(var + LN_EPS);
#pragma unroll
    for (int p = 0; p < 3; ++p) {
        int c = lane * 4 + p * 256;
        float4 w = *(const float4*)(nw + c);
        float4 bb = *(const float4*)(nb + c);
        union { ushort4 q; ushort u[4]; } o;
        o.u[0] = f2hu((g[p*4+0] - mu) * rstd * w.x + bb.x);
        o.u[1] = f2hu((g[p*4+1] - mu) * rstd * w.y + bb.y);
        o.u[2] = f2hu((g[p*4+2] - mu) * rstd * w.z + bb.z);
        o.u[3] = f2hu((g[p*4+3] - mu) * rstd * w.w + bb.w);
        *(ushort4*)(gnbuf + base + c) = o.q;
    }
}

extern "C" void kernel_launch(void* const* d_in, const int* in_sizes, int n_in,
                              void* d_out, int out_size, void* d_ws, size_t ws_size,
                              hipStream_t stream)
{
    const float* x         = (const float*)d_in[0];
    const float* in_proj_w = (const float*)d_in[1];
    const float* conv_w    = (const float*)d_in[2];
    const float* conv_b    = (const float*)d_in[3];
    const float* dt_bias   = (const float*)d_in[4];
    const float* A_log     = (const float*)d_in[5];
    const float* Dp        = (const float*)d_in[6];
    const float* norm_w    = (const float*)d_in[7];
    const float* norm_b    = (const float*)d_in[8];
    const float* out_proj_w= (const float*)d_in[9];

    char* wsb = (char*)d_ws;
    float*  dtbuf   = (float*) (wsb + 0);
    float*  cwr     = (float*) (wsb + 1204224);
    ushort* w1      = (ushort*)(wsb + 2777088);
    ushort* w2      = (ushort*)(wsb + 4153344);
    ushort* zbuf    = (ushort*)(wsb + 4743168);
    ushort* xbcraw  = (ushort*)(wsb + 43278336);
    ushort* xbcconv = (ushort*)(wsb + 88236032);
    ushort* x16     = xbcconv;
    ushort* hT      = xbcraw;
    float*  hpart   = (float*)(wsb + 44851200);
    ushort* dxp     = (ushort*)d_out;
    ushort* ybuf    = (ushort*)d_out;
    ushort* gnbuf   = xbcraw;

    k_cast_x <<<MTOT * DMODEL / 4 / 256, 256, 0, stream>>>(
        (const float4*)x, (ushort4*)x16);
    k_cast_w<<<(W1Q + W2Q + CWQ + 255) / 256, 256, 0, stream>>>(
        in_proj_w, out_proj_w, conv_w, (ushort4*)w1, (ushort4*)w2, cwr);

    k_gemm1_mfma<<<G1_NWG, 256, 0, stream>>>(
        x16, w1, dt_bias, zbuf, xbcraw, dtbuf);

    k_conv<<<MTOT / 4 * NCG / 256, 256, 0, stream>>>(
        xbcraw, cwr, conv_b, xbcconv);
    k_dxpool<<<MTOT / 4 * NDG / 256, 256, 0, stream>>>(
        xbcconv, dtbuf, A_log, dxp);
    k_hstate_mfma<<<dim3(SPLITL, BB * NH), 256, 0, stream>>>(
        xbcconv, dxp, hpart);
    k_hprep<<<96 * 4096 / 256, 256, 0, stream>>>(hpart, hT);
    k_chy_mfma<<<dim3(13, BB * NH), 256, 0, stream>>>(
        xbcconv, hT, Dp, ybuf);
    k_gln<<<MTOT / 4, 256, 0, stream>>>(
        ybuf, zbuf, norm_w, norm_b, gnbuf);
    k_gemm2_mfma<<<G2_NWG, 256, 0, stream>>>(
        gnbuf, w2, (float*)d_out);
}

// Round 17
// 351.716 us; speedup vs baseline: 1.3651x; 1.3651x over previous
//
#include <hip/hip_runtime.h>
#include <hip/hip_bf16.h>
#include <math.h>

// Problem constants (fixed by setup_inputs: B=8, H=W=56)
#define BB 8
#define HH 56
#define WW 56
#define LL (HH*WW)          // 3136
#define DMODEL 384
#define DINNER 768
#define NH 12
#define HD 64
#define DS 64
#define CDIM (DINNER + 2*DS)    // 896
#define NPROJ (2*DINNER + 2*DS + NH) // 1676
#define NPAD 1792           // NPROJ padded to multiple of 128
#define MTOT (BB*LL)        // 25088
#define LN_EPS 1e-5f
#define NCG (CDIM/8)        // 112 channel-groups for conv
#define NDG (DINNER/8)      // 96 channel-groups for dxpool
#define SPLITL 7            // L-chunks for hstate (3136/7 = 448)

typedef __attribute__((ext_vector_type(8))) _Float16 f16x8;
typedef __attribute__((ext_vector_type(4))) float f32x4;

// f16 <-> f32 with bits in ushort
__device__ __forceinline__ ushort f2hu(float v) {
    union { _Float16 h; ushort u; } cv; cv.h = (_Float16)v; return cv.u;
}
__device__ __forceinline__ float hu2f(ushort u) {
    union { ushort u; _Float16 h; } cv; cv.u = u; return (float)cv.h;
}

// async global->LDS, 16B per lane; LDS dest = uniform base + lane*16
__device__ __forceinline__ void gload_lds16(const ushort* gp, ushort* lp) {
    __builtin_amdgcn_global_load_lds(
        (const __attribute__((address_space(1))) void*)gp,
        (__attribute__((address_space(3))) void*)lp, 16, 0, 0);
}

// bijective XCD-chunk swizzle (m204): consecutive work-ids within one XCD
__device__ __forceinline__ int xcd_swz(int bid, int nwg) {
    int q = nwg >> 3, r = nwg & 7;
    int xcd = bid & 7, idx = bid >> 3;
    return (xcd < r ? xcd * (q + 1) : r * (q + 1) + (xcd - r) * q) + idx;
}

// ---------------- cast kernels: fp32 -> f16 -------------------------------------
__global__ __launch_bounds__(256) void k_cast_x(
    const float4* __restrict__ in, ushort4* __restrict__ out)
{
    int i = blockIdx.x * 256 + threadIdx.x;    // grid sized exactly
    float4 v = in[i];
    ushort4 h;
    h.x = f2hu(v.x); h.y = f2hu(v.y); h.z = f2hu(v.z); h.w = f2hu(v.w);
    out[i] = h;
}

// merged weight cast: w1 (padded), w2, and conv-weight reorg cwr[cg][tap][8ch] fp32
#define W1Q (NPAD*DMODEL/4)    // 172032
#define W2Q (DMODEL*DINNER/4)  // 73728
#define CWQ (NCG*72/4)         // 2016
__global__ __launch_bounds__(256) void k_cast_w(
    const float* __restrict__ w1src, const float* __restrict__ w2src,
    const float* __restrict__ cwsrc,
    ushort4* __restrict__ w1dst, ushort4* __restrict__ w2dst,
    float* __restrict__ cwrdst)
{
    int i = blockIdx.x * 256 + threadIdx.x;   // over W1Q+W2Q+CWQ
    if (i < W1Q) {
        int n = i / (DMODEL / 4);
        int k = (i % (DMODEL / 4)) * 4;
        ushort4 h = {0,0,0,0};
        if (n < NPROJ) {
            float4 v = *(const float4*)(w1src + (size_t)n * DMODEL + k);
            h.x = f2hu(v.x); h.y = f2hu(v.y); h.z = f2hu(v.z); h.w = f2hu(v.w);
        }
        w1dst[i] = h;
    } else if (i < W1Q + W2Q) {
        int t = i - W1Q;
        float4 v = ((const float4*)w2src)[t];
        ushort4 h;
        h.x = f2hu(v.x); h.y = f2hu(v.y); h.z = f2hu(v.z); h.w = f2hu(v.w);
        w2dst[t] = h;
    } else if (i < W1Q + W2Q + CWQ) {
        int t = i - W1Q - W2Q;
#pragma unroll
        for (int k = 0; k < 4; ++k) {
            int e = 4 * t + k;                // index into cwr: cg*72 + tap*8 + q
            int cgx = e / 72;
            int rr = e % 72;
            int tap = rr >> 3, q = rr & 7;
            cwrdst[e] = cwsrc[(cgx * 8 + q) * 9 + tap];
        }
    }
}

// ---------------- GEMM1 (MFMA f16, BK=64, XCD-chunked, XOR-swizzled LDS) --------
// Measured best: 75-77 us, SQ_LDS_BANK_CONFLICT = 0 (rounds 12/13 profiles).
#define G1_NT (NPAD/128)    // 14 n-tiles
#define G1_NWG (G1_NT * (MTOT/128))  // 2744
__global__ __launch_bounds__(256) void k_gemm1_mfma(
    const ushort* __restrict__ xh, const ushort* __restrict__ wh,
    const float* __restrict__ dt_bias,
    ushort* __restrict__ zbuf, ushort* __restrict__ xbcbuf, float* __restrict__ dtbuf)
{
    __shared__ ushort As[2][128 * 32];
    __shared__ ushort Bs[2][128 * 32];
    const int w = xcd_swz(blockIdx.x, G1_NWG);
    const int m0 = (w / G1_NT) * 128;
    const int n0 = (w % G1_NT) * 128;     // n-major: 14 consecutive share A-panel
    const int tid = threadIdx.x;
    const int wid = tid >> 6;
    const int lane = tid & 63;
    const int r = lane & 15;
    const int quad = lane >> 4;
    const int wm = (wid >> 1) * 64;
    const int wn = (wid & 1) * 64;
    const int lrow = lane >> 2;       // 0..15 row within 16-row stage stripe
    const int lcol = (((lane & 3) ^ ((lane >> 3) & 3)) * 8);
    const int sxr = (r >> 1) & 3;

    f32x4 acc[4][4];
#pragma unroll
    for (int i = 0; i < 4; ++i)
#pragma unroll
        for (int j = 0; j < 4; ++j) acc[i][j] = (f32x4){0.f, 0.f, 0.f, 0.f};

    for (int k0 = 0; k0 < DMODEL; k0 += 64) {
#pragma unroll
        for (int half = 0; half < 2; ++half) {
#pragma unroll
            for (int inst = 0; inst < 2; ++inst) {
                const int R = wid * 32 + inst * 16;
                gload_lds16(xh + (size_t)(m0 + R + lrow) * DMODEL + k0 + half * 32 + lcol,
                            As[half] + R * 32);
                gload_lds16(wh + (size_t)(n0 + R + lrow) * DMODEL + k0 + half * 32 + lcol,
                            Bs[half] + R * 32);
            }
        }
        __syncthreads();   // vmcnt(0) drain: both K-halves resident

#pragma unroll
        for (int kk = 0; kk < 2; ++kk) {
            f16x8 af[4], bfr[4];
#pragma unroll
            for (int t = 0; t < 4; ++t) {
                af[t]  = *(const f16x8*)(As[kk] + (wm + t * 16 + r) * 32 + ((quad ^ sxr) * 8));
                bfr[t] = *(const f16x8*)(Bs[kk] + (wn + t * 16 + r) * 32 + ((quad ^ sxr) * 8));
            }
#pragma unroll
            for (int i = 0; i < 4; ++i)
#pragma unroll
                for (int j = 0; j < 4; ++j)
                    acc[i][j] = __builtin_amdgcn_mfma_f32_16x16x32_f16(af[i], bfr[j], acc[i][j], 0, 0, 0);
        }
        __syncthreads();   // safe to overwrite LDS next step
    }
#pragma unroll
    for (int i = 0; i < 4; ++i) {
#pragma unroll
        for (int j = 0; j < 4; ++j) {
            int n = n0 + wn + j * 16 + r;
            if (n >= NPROJ) continue;
#pragma unroll
            for (int v = 0; v < 4; ++v) {
                int m = m0 + wm + i * 16 + quad * 4 + v;
                float val = acc[i][j][v];
                if (n < DINNER) {
                    zbuf[(size_t)m * DINNER + n] = f2hu(val);
                } else if (n < DINNER + CDIM) {
                    xbcbuf[(size_t)m * CDIM + (n - DINNER)] = f2hu(val);
                } else {
                    int h = n - (DINNER + CDIM);
                    float t = val + dt_bias[h];
                    float sp = (t > 20.f) ? t : log1pf(expf(t));
                    dtbuf[(size_t)m * NH + h] = sp;
                }
            }
        }
    }
}

// ---------------- GEMM2 (MFMA f16, BK=64, XCD-chunked, XOR-swizzled LDS) --------
#define G2_NT (DMODEL/128)  // 3 n-tiles
#define G2_NWG (G2_NT * (MTOT/128))  // 588
__global__ __launch_bounds__(256) void k_gemm2_mfma(
    const ushort* __restrict__ gn, const ushort* __restrict__ wh,
    float* __restrict__ out)
{
    __shared__ ushort As[2][128 * 32];
    __shared__ ushort Bs[2][128 * 32];
    const int w = xcd_swz(blockIdx.x, G2_NWG);
    const int m0 = (w / G2_NT) * 128;
    const int n0 = (w % G2_NT) * 128;
    const int tid = threadIdx.x;
    const int wid = tid >> 6;
    const int lane = tid & 63;
    const int r = lane & 15;
    const int quad = lane >> 4;
    const int wm = (wid >> 1) * 64;
    const int wn = (wid & 1) * 64;
    const int lrow = lane >> 2;
    const int lcol = (((lane & 3) ^ ((lane >> 3) & 3)) * 8);
    const int sxr = (r >> 1) & 3;

    f32x4 acc[4][4];
#pragma unroll
    for (int i = 0; i < 4; ++i)
#pragma unroll
        for (int j = 0; j < 4; ++j) acc[i][j] = (f32x4){0.f, 0.f, 0.f, 0.f};

    for (int k0 = 0; k0 < DINNER; k0 += 64) {
#pragma unroll
        for (int half = 0; half < 2; ++half) {
#pragma unroll
            for (int inst = 0; inst < 2; ++inst) {
                const int R = wid * 32 + inst * 16;
                gload_lds16(gn + (size_t)(m0 + R + lrow) * DINNER + k0 + half * 32 + lcol,
                            As[half] + R * 32);
                gload_lds16(wh + (size_t)(n0 + R + lrow) * DINNER + k0 + half * 32 + lcol,
                            Bs[half] + R * 32);
            }
        }
        __syncthreads();

#pragma unroll
        for (int kk = 0; kk < 2; ++kk) {
            f16x8 af[4], bfr[4];
#pragma unroll
            for (int t = 0; t < 4; ++t) {
                af[t]  = *(const f16x8*)(As[kk] + (wm + t * 16 + r) * 32 + ((quad ^ sxr) * 8));
                bfr[t] = *(const f16x8*)(Bs[kk] + (wn + t * 16 + r) * 32 + ((quad ^ sxr) * 8));
            }
#pragma unroll
            for (int i = 0; i < 4; ++i)
#pragma unroll
                for (int j = 0; j < 4; ++j)
                    acc[i][j] = __builtin_amdgcn_mfma_f32_16x16x32_f16(af[i], bfr[j], acc[i][j], 0, 0, 0);
        }
        __syncthreads();
    }
#pragma unroll
    for (int i = 0; i < 4; ++i) {
#pragma unroll
        for (int j = 0; j < 4; ++j) {
            int n = n0 + wn + j * 16 + r;
#pragma unroll
            for (int v = 0; v < 4; ++v) {
                int m = m0 + wm + i * 16 + quad * 4 + v;
                out[(size_t)m * DMODEL + n] = acc[i][j][v];
            }
        }
    }
}

// ---------------- depthwise 3x3 conv + bias + SiLU, 4 pixels x 8 ch per thread --
// cwr layout: [cg][tap 0..8][8ch] fp32 (row's 24 weights = 6 contiguous float4).
__global__ __launch_bounds__(256) void k_conv(
    const ushort* __restrict__ xbc, const float* __restrict__ cwr,
    const float* __restrict__ cb, ushort* __restrict__ out)
{
    const int gid = blockIdx.x * 256 + threadIdx.x;  // over MTOT/4*NCG = 702,464
    const int cg  = gid % NCG;
    const int pq  = gid / NCG;
    const int b   = pq / (LL / 4);
    const int rem = pq % (LL / 4);
    const int i   = rem / (WW / 4);
    const int j0  = (rem % (WW / 4)) * 4;
    const int c0  = cg * 8;

    float acc[4][8];
    {
        float4 b0 = *(const float4*)(cb + c0);
        float4 b1 = *(const float4*)(cb + c0 + 4);
#pragma unroll
        for (int p = 0; p < 4; ++p) {
            acc[p][0]=b0.x; acc[p][1]=b0.y; acc[p][2]=b0.z; acc[p][3]=b0.w;
            acc[p][4]=b1.x; acc[p][5]=b1.y; acc[p][6]=b1.z; acc[p][7]=b1.w;
        }
    }
    const size_t rowbase = (size_t)b * LL;
#pragma unroll
    for (int ky = 0; ky < 3; ++ky) {
        int ii = i + ky - 1;
        if (ii < 0 || ii >= HH) continue;
        float w[24];
        const float* wr = cwr + (cg * 9 + ky * 3) * 8;
#pragma unroll
        for (int t = 0; t < 6; ++t)
            *(float4*)(w + t * 4) = *(const float4*)(wr + t * 4);
        float xc[6][8];
#pragma unroll
        for (int col = 0; col < 6; ++col) {
            int jj = j0 - 1 + col;
            if (jj >= 0 && jj < WW) {
                union { int4 q; ushort u[8]; } xv;
                xv.q = *(const int4*)(xbc + (rowbase + ii * WW + jj) * CDIM + c0);
#pragma unroll
                for (int q = 0; q < 8; ++q) xc[col][q] = hu2f(xv.u[q]);
            } else {
#pragma unroll
                for (int q = 0; q < 8; ++q) xc[col][q] = 0.f;
            }
        }
#pragma unroll
        for (int p = 0; p < 4; ++p)
#pragma unroll
            for (int kx = 0; kx < 3; ++kx)
#pragma unroll
                for (int q = 0; q < 8; ++q)
                    acc[p][q] += w[kx * 8 + q] * xc[p + kx][q];
    }
#pragma unroll
    for (int p = 0; p < 4; ++p) {
        union { int4 q; ushort u[8]; } o;
#pragma unroll
        for (int q = 0; q < 8; ++q) {
            float s = acc[p][q] / (1.f + expf(-acc[p][q]));
            o.u[q] = f2hu(s);
        }
        *(int4*)(out + (rowbase + i * WW + j0 + p) * CDIM + c0) = o.q;
    }
}

// ---------------- fused dx + 3x3 count-norm avg pool, 4 pixels x 8 ch -----------
__global__ __launch_bounds__(256) void k_dxpool(
    const ushort* __restrict__ xbc_conv, const float* __restrict__ dtbuf,
    const float* __restrict__ A_log, ushort* __restrict__ dxp)
{
    const int gid = blockIdx.x * 256 + threadIdx.x;  // over MTOT/4*NDG = 602,112
    const int cg  = gid % NDG;
    const int pq  = gid / NDG;
    const int b   = pq / (LL / 4);
    const int rem = pq % (LL / 4);
    const int i   = rem / (WW / 4);
    const int j0  = (rem % (WW / 4)) * 4;
    const int c0  = cg * 8;         // channel in [0,768)
    const int h   = c0 >> 6;

    float Ah[8];
    {
        float4 a0 = *(const float4*)(A_log + c0);
        float4 a1 = *(const float4*)(A_log + c0 + 4);
        Ah[0]=a0.x; Ah[1]=a0.y; Ah[2]=a0.z; Ah[3]=a0.w;
        Ah[4]=a1.x; Ah[5]=a1.y; Ah[6]=a1.z; Ah[7]=a1.w;
    }
#pragma unroll
    for (int q = 0; q < 8; ++q) Ah[q] = -expf(Ah[q]);

    float sum[4][8];
#pragma unroll
    for (int p = 0; p < 4; ++p)
#pragma unroll
        for (int q = 0; q < 8; ++q) sum[p][q] = 0.f;

    const size_t rowbase = (size_t)b * LL;
#pragma unroll
    for (int ky = 0; ky < 3; ++ky) {
        int ii = i + ky - 1;
        if (ii < 0 || ii >= HH) continue;
        float dtv[6];
        float xc[6][8];
#pragma unroll
        for (int col = 0; col < 6; ++col) {
            int jj = j0 - 1 + col;
            if (jj >= 0 && jj < WW) {
                dtv[col] = dtbuf[(rowbase + ii * WW + jj) * NH + h];
                union { int4 q; ushort u[8]; } xv;
                xv.q = *(const int4*)(xbc_conv + (rowbase + ii * WW + jj) * CDIM + c0);
#pragma unroll
                for (int q = 0; q < 8; ++q) xc[col][q] = hu2f(xv.u[q]);
            } else {
                dtv[col] = 0.f;
#pragma unroll
                for (int q = 0; q < 8; ++q) xc[col][q] = 0.f;
            }
        }
#pragma unroll
        for (int p = 0; p < 4; ++p)
#pragma unroll
            for (int kx = 0; kx < 3; ++kx)
#pragma unroll
                for (int q = 0; q < 8; ++q)
                    sum[p][q] += dtv[p + kx] * xc[p + kx][q];
    }
    const int rv = 3 - (i == 0) - (i == HH - 1);
#pragma unroll
    for (int p = 0; p < 4; ++p) {
        int j = j0 + p;
        int cv = 3 - (j == 0) - (j == WW - 1);
        float inv = 1.f / (float)(rv * cv);
        union { int4 q; ushort u[8]; } o;
#pragma unroll
        for (int q = 0; q < 8; ++q)
            o.u[q] = f2hu(Ah[q] * sum[p][q] * inv);
        *(int4*)(dxp + (((size_t)b * NH + h) * LL + i * WW + j) * HD + (c0 & 63)) = o.q;
    }
}

// ---------------- h_state via MFMA (no atomics): Ht_part[d][s] ------------------
#define LDSP 33
__global__ __launch_bounds__(256) void k_hstate_mfma(
    const ushort* __restrict__ xbc_conv, const ushort* __restrict__ dxp,
    float* __restrict__ hpart)
{
    __shared__ ushort DsT[64 * LDSP];   // [d][l]
    __shared__ ushort BsT[64 * LDSP];   // [s][l]
    const int lc = blockIdx.x;          // 0..6
    const int bh = blockIdx.y;          // 0..95
    const int b = bh / NH;
    const int tid = threadIdx.x;
    const int wid = tid >> 6;
    const int lane = tid & 63;
    const int r = lane & 15;
    const int quad = lane >> 4;
    const int wd = (wid >> 1) * 32;     // d-offset of wave quadrant
    const int wsn = (wid & 1) * 32;     // s-offset
    const int lt = tid >> 3;            // 0..31 (l within tile)
    const int sg = (tid & 7) * 8;       // 0,8,..,56 (channel group)

    f32x4 acc[2][2];
#pragma unroll
    for (int i = 0; i < 2; ++i)
#pragma unroll
        for (int j = 0; j < 2; ++j) acc[i][j] = (f32x4){0.f, 0.f, 0.f, 0.f};

    const int l_base = lc * (LL / SPLITL);    // 448-chunk
    for (int step = 0; step < (LL / SPLITL) / 32; ++step) {
        int l0 = l_base + step * 32;
        union { int4 q; ushort u[8]; } dv, bv;
        dv.q = *(const int4*)(dxp + (((size_t)bh) * LL + l0 + lt) * HD + sg);
        bv.q = *(const int4*)(xbc_conv + ((size_t)(b * LL + l0 + lt)) * CDIM + DINNER + sg);
        __syncthreads();
#pragma unroll
        for (int q = 0; q < 8; ++q) {
            DsT[(sg + q) * LDSP + lt] = dv.u[q];
            BsT[(sg + q) * LDSP + lt] = bv.u[q];
        }
        __syncthreads();
        f16x8 af[2], bf[2];
#pragma unroll
        for (int t = 0; t < 2; ++t) {
            af[t] = *(const f16x8*)(DsT + (wd + t * 16 + r) * LDSP + quad * 8);
            bf[t] = *(const f16x8*)(BsT + (wsn + t * 16 + r) * LDSP + quad * 8);
        }
#pragma unroll
        for (int i = 0; i < 2; ++i)
#pragma unroll
            for (int j = 0; j < 2; ++j)
                acc[i][j] = __builtin_amdgcn_mfma_f32_16x16x32_f16(af[i], bf[j], acc[i][j], 0, 0, 0);
    }
    float* outp = hpart + ((size_t)(lc * 96 + bh) << 12);
#pragma unroll
    for (int i = 0; i < 2; ++i)
#pragma unroll
        for (int j = 0; j < 2; ++j)
#pragma unroll
            for (int v = 0; v < 4; ++v)
                outp[(wd + i * 16 + quad * 4 + v) * 64 + (wsn + j * 16 + r)] = acc[i][j][v];
}

// ---------------- h-prep: reduce 7 partials [d][s] -> hT f16 [bh][d][s] ---------
__global__ __launch_bounds__(256) void k_hprep(
    const float* __restrict__ hpart, ushort* __restrict__ hT)
{
    int i = blockIdx.x * 256 + threadIdx.x;   // over 96*4096 = 393216
    int bh = i >> 12;
    int rem = i & 4095;                       // = d*64+s
    float v = 0.f;
#pragma unroll
    for (int lc = 0; lc < SPLITL; ++lc)
        v += hpart[((size_t)(lc * 96 + bh) << 12) + rem];
    hT[i] = f2hu(v);
}

// ---------------- Ch + y via MFMA (v2: LDS-staged Cm, verified swizzle) ---------
#define HTW 72
__global__ __launch_bounds__(256) void k_chy_mfma(
    const ushort* __restrict__ xbc_conv, const ushort* __restrict__ hT,
    const float* __restrict__ Dp, ushort* __restrict__ ybuf)
{
    __shared__ ushort Cs[2][256 * 32];  // Cm [256 l][64 s] as two 32-wide subtiles, 32 KB
    __shared__ ushort Hs[64 * HTW];     // 9 KB
    const int bh = blockIdx.y;
    const int b = bh / NH, h = bh % NH;
    const int tid = threadIdx.x;
    const int wid = tid >> 6;
    const int lane = tid & 63;
    const int r = lane & 15;
    const int quad = lane >> 4;
    const int lrow = lane >> 2;                              // 16-row stage stripe
    const int lcol = (((lane & 3) ^ ((lane >> 3) & 3)) * 8); // pre-swizzled source slot
    const int sxr = (r >> 1) & 3;                            // read-side involution

    for (int idx = tid; idx < 512; idx += 256) {
        int row = idx >> 3, c8 = (idx & 7) * 8;
        *(int4*)(Hs + row * HTW + c8) = *(const int4*)(hT + ((size_t)bh << 12) + row * 64 + c8);
    }

    // stage Cm[lbase .. lbase+255][0..63] (two 32-wide swizzled subtiles)
    const int lbase = blockIdx.x * 256;
#pragma unroll
    for (int inst = 0; inst < 4; ++inst) {
        const int R = wid * 64 + inst * 16;                  // 16-row stripe per instr
        if (lbase + R + 16 <= LL) {                          // wave-uniform validity
#pragma unroll
            for (int kk = 0; kk < 2; ++kk) {
                gload_lds16(xbc_conv + ((size_t)(b * LL + lbase + R + lrow)) * CDIM
                                      + DINNER + DS + kk * 32 + lcol,
                            Cs[kk] + R * 32);
            }
        }
    }
    __syncthreads();   // Hs + Cs resident (vmcnt+lgkm drained)

    const int chunk = blockIdx.x * 4 + wid;   // 0..48 valid (49 chunks of 64 l-rows)
    if (chunk >= 49) return;                  // no barriers after this point
    const int l0 = chunk * 64;
    const int wl = wid * 64;                  // l-offset within staged 256 rows

    f32x4 acc[4][4];
#pragma unroll
    for (int i = 0; i < 4; ++i)
#pragma unroll
        for (int j = 0; j < 4; ++j) acc[i][j] = (f32x4){0.f, 0.f, 0.f, 0.f};

#pragma unroll
    for (int kk = 0; kk < 2; ++kk) {          // K=64 in two 32-steps
        f16x8 af[4], bfr[4];
#pragma unroll
        for (int t = 0; t < 4; ++t) {
            af[t]  = *(const f16x8*)(Cs[kk] + (wl + t * 16 + r) * 32 + ((quad ^ sxr) * 8));
            bfr[t] = *(const f16x8*)(Hs + (t * 16 + r) * HTW + kk * 32 + quad * 8);
        }
#pragma unroll
        for (int i = 0; i < 4; ++i)
#pragma unroll
            for (int j = 0; j < 4; ++j)
                acc[i][j] = __builtin_amdgcn_mfma_f32_16x16x32_f16(af[i], bfr[j], acc[i][j], 0, 0, 0);
    }
    const float Dh = Dp[h];
#pragma unroll
    for (int i = 0; i < 4; ++i) {
#pragma unroll
        for (int j = 0; j < 4; ++j) {
            int d = j * 16 + r;
#pragma unroll
            for (int v = 0; v < 4; ++v) {
                int l = l0 + i * 16 + quad * 4 + v;
                float xv = hu2f(xbc_conv[((size_t)(b * LL + l)) * CDIM + h * HD + d]);
                ybuf[((size_t)(b * LL + l)) * DINNER + h * HD + d] = f2hu(acc[i][j][v] + xv * Dh);
            }
        }
    }
}

// ---------------- g = y*silu(z); LayerNorm(768), wave-per-row -------------------
__global__ __launch_bounds__(256) void k_gln(
    const ushort* __restrict__ ybuf, const ushort* __restrict__ zbuf,
    const float* __restrict__ nw, const float* __restrict__ nb,
    ushort* __restrict__ gnbuf)
{
    const int row = blockIdx.x * 4 + (threadIdx.x >> 6);
    const int lane = threadIdx.x & 63;
    const size_t base = (size_t)row * DINNER;

    float g[12];
    float sum = 0.f, sumsq = 0.f;
#pragma unroll
    for (int p = 0; p < 3; ++p) {
        int c = lane * 4 + p * 256;
        union { ushort4 q; ushort u[4]; } yv, zv;
        yv.q = *(const ushort4*)(ybuf + base + c);
        zv.q = *(const ushort4*)(zbuf + base + c);
#pragma unroll
        for (int q = 0; q < 4; ++q) {
            float y = hu2f(yv.u[q]);
            float z = hu2f(zv.u[q]);
            float gv = y * (z / (1.f + expf(-z)));
            g[p * 4 + q] = gv;
            sum += gv;
            sumsq += gv * gv;
        }
    }
#pragma unroll
    for (int off = 32; off > 0; off >>= 1) {
        sum += __shfl_xor(sum, off, 64);
        sumsq += __shfl_xor(sumsq, off, 64);
    }
    const float mu = sum / (float)DINNER;
    const float var = sumsq / (float)DINNER - mu * mu;
    const float rstd = rsqrtf(var + LN_EPS);
#pragma unroll
    for (int p = 0; p < 3; ++p) {
        int c = lane * 4 + p * 256;
        float4 w = *(const float4*)(nw + c);
        float4 bb = *(const float4*)(nb + c);
        union { ushort4 q; ushort u[4]; } o;
        o.u[0] = f2hu((g[p*4+0] - mu) * rstd * w.x + bb.x);
        o.u[1] = f2hu((g[p*4+1] - mu) * rstd * w.y + bb.y);
        o.u[2] = f2hu((g[p*4+2] - mu) * rstd * w.z + bb.z);
        o.u[3] = f2hu((g[p*4+3] - mu) * rstd * w.w + bb.w);
        *(ushort4*)(gnbuf + base + c) = o.q;
    }
}

extern "C" void kernel_launch(void* const* d_in, const int* in_sizes, int n_in,
                              void* d_out, int out_size, void* d_ws, size_t ws_size,
                              hipStream_t stream)
{
    const float* x         = (const float*)d_in[0];
    const float* in_proj_w = (const float*)d_in[1];
    const float* conv_w    = (const float*)d_in[2];
    const float* conv_b    = (const float*)d_in[3];
    const float* dt_bias   = (const float*)d_in[4];
    const float* A_log     = (const float*)d_in[5];
    const float* Dp        = (const float*)d_in[6];
    const float* norm_w    = (const float*)d_in[7];
    const float* norm_b    = (const float*)d_in[8];
    const float* out_proj_w= (const float*)d_in[9];

    // workspace layout (bytes) — same offsets as known-good rounds 7-9:
    char* wsb = (char*)d_ws;
    float*  dtbuf   = (float*) (wsb + 0);
    float*  cwr     = (float*) (wsb + 1204224);
    ushort* w1      = (ushort*)(wsb + 2777088);
    ushort* w2      = (ushort*)(wsb + 4153344);
    ushort* zbuf    = (ushort*)(wsb + 4743168);
    ushort* xbcraw  = (ushort*)(wsb + 43278336);
    ushort* xbcconv = (ushort*)(wsb + 88236032);
    ushort* x16     = xbcconv;
    ushort* hT      = xbcraw;
    float*  hpart   = (float*)(wsb + 44851200);
    ushort* dxp     = (ushort*)d_out;
    ushort* ybuf    = (ushort*)d_out;
    ushort* gnbuf   = xbcraw;

    k_cast_x <<<MTOT * DMODEL / 4 / 256, 256, 0, stream>>>(
        (const float4*)x, (ushort4*)x16);
    k_cast_w<<<(W1Q + W2Q + CWQ + 255) / 256, 256, 0, stream>>>(
        in_proj_w, out_proj_w, conv_w, (ushort4*)w1, (ushort4*)w2, cwr);

    k_gemm1_mfma<<<G1_NWG, 256, 0, stream>>>(
        x16, w1, dt_bias, zbuf, xbcraw, dtbuf);

    k_conv<<<MTOT / 4 * NCG / 256, 256, 0, stream>>>(
        xbcraw, cwr, conv_b, xbcconv);
    k_dxpool<<<MTOT / 4 * NDG / 256, 256, 0, stream>>>(
        xbcconv, dtbuf, A_log, dxp);
    k_hstate_mfma<<<dim3(SPLITL, BB * NH), 256, 0, stream>>>(
        xbcconv, dxp, hpart);
    k_hprep<<<96 * 4096 / 256, 256, 0, stream>>>(hpart, hT);
    k_chy_mfma<<<dim3(13, BB * NH), 256, 0, stream>>>(
        xbcconv, hT, Dp, ybuf);
    k_gln<<<MTOT / 4, 256, 0, stream>>>(
        ybuf, zbuf, norm_w, norm_b, gnbuf);
    k_gemm2_mfma<<<G2_NWG, 256, 0, stream>>>(
        gnbuf, w2, (float*)d_out);
}